// Round 21
// baseline (264.619 us; speedup 1.0000x reference)
//
#include <hip/hip_runtime.h>
#include <hip/hip_fp16.h>
#include <cmath>

#define TPB 256
#define NSLOPE 0.2f
#define SEPS 1e-16f

#define BSH 7                 // nodes per bucket = 128
#define BNODES 128
#define NBMAX 1024            // supports N up to 131072 at BSH=7
#define NCHUNK 512            // blocks for bucket scatter
#define SCTPB 1024            // bscatter threads
#define SCSTAGE 3360          // bscatter per-chunk LDS staging (chunk=3321 at N=100k)
#define STAGE 2816            // per-bucket LDS sorted-edge staging (cap=2688 at N=100k)
#define MAXDEG 96             // per-wave LDS score staging cap (P[deg>96] ~ 0 for Poisson(17))

__device__ __forceinline__ float lrelu(float v) { return v > 0.f ? v : NSLOPE * v; }
__device__ __forceinline__ float elu1(float v)  { return v > 0.f ? v : expm1f(v); }
__device__ __forceinline__ float elu1f(float v) { return v > 0.f ? v : __expf(v) - 1.f; }

// ---- prep: SD[0..3]=S1[h], SD[4..7]=D1[h]; init padded-bucket cursors (1/64B line) ----
__global__ void k_prep(const float* __restrict__ W1, const float* __restrict__ as1,
                       const float* __restrict__ ad1, float* __restrict__ SD,
                       unsigned* __restrict__ bucketCursor, int NB, unsigned cap) {
    int t = threadIdx.x;
    for (int i = t; i < NB; i += blockDim.x) bucketCursor[(size_t)i * 16] = (unsigned)i * cap;
    if (t < 8) {
        int h = t & 3;
        const float* att = (t >= 4) ? ad1 : as1;
        float acc = 0.f;
        #pragma unroll
        for (int c = 0; c < 8; ++c) acc += W1[h*8+c] * att[h*8+c];
        SD[t] = acc;
    }
}

// ---- bucket scatter: hist -> scan -> claim -> LDS bucket-sort of the chunk ->
//      LINEAR bucket-coalesced global writes ----
__global__ void k_bscatter(const int* __restrict__ srcI, const int* __restrict__ dstI,
                           int E, int N, int NB, int chunk,
                           unsigned* __restrict__ bucketCursor, int* __restrict__ pk) {
    __shared__ int cnt[NBMAX];
    __shared__ unsigned base[NBMAX];      // scan scratch, then claimed bases
    __shared__ int offl[NBMAX];           // local exclusive prefix
    __shared__ int rval[SCSTAGE];
    __shared__ unsigned short rbkt[SCSTAGE];
    int t = threadIdx.x;
    int ET = E + N;
    int beg = blockIdx.x * chunk;
    int end = min(beg + chunk, ET);
    int m = end - beg;
    for (int i = t; i < NBMAX; i += blockDim.x) cnt[i] = 0;
    __syncthreads();
    for (int e = beg + t; e < end; e += blockDim.x) {
        int d = (e < E) ? dstI[e] : (e - E);
        atomicAdd(&cnt[d >> BSH], 1);
    }
    __syncthreads();
    int v = (t < NBMAX) ? cnt[t] : 0;
    if (t < NBMAX) base[t] = (unsigned)v;
    __syncthreads();
    for (int off = 1; off < NBMAX; off <<= 1) {
        unsigned u = (t >= off && t < NBMAX) ? base[t - off] : 0u;
        __syncthreads();
        if (t < NBMAX) base[t] += u;
        __syncthreads();
    }
    if (t < NBMAX) offl[t] = (int)base[t] - v;   // exclusive prefix within chunk
    __syncthreads();
    if (t < NB) {
        base[t] = v ? atomicAdd(&bucketCursor[(size_t)t * 16], (unsigned)v) : 0u;
        cnt[t] = 0;
    }
    __syncthreads();
    if (m <= SCSTAGE) {
        for (int e = beg + t; e < end; e += blockDim.x) {
            int s, d;
            if (e < E) { s = srcI[e]; d = dstI[e]; } else { s = d = e - E; }
            int b = d >> BSH;
            int r = atomicAdd(&cnt[b], 1);
            int slot = offl[b] + r;
            rval[slot] = (s << BSH) | (d & (BNODES - 1));
            rbkt[slot] = (unsigned short)b;
        }
        __syncthreads();
        for (int slot = t; slot < m; slot += blockDim.x) {
            int b = rbkt[slot];
            pk[base[b] + (unsigned)(slot - offl[b])] = rval[slot];
        }
    } else {
        for (int e = beg + t; e < end; e += blockDim.x) {
            int s, d;
            if (e < E) { s = srcI[e]; d = dstI[e]; } else { s = d = e - E; }
            int b = d >> BSH;
            int r = atomicAdd(&cnt[b], 1);
            pk[base[b] + (unsigned)r] = (s << BSH) | (d & (BNODES - 1));
        }
    }
}

// ---- merged sort + layer-1 + h2/att: pk read twice from global (L2-warm);
//      sorted list lives in LDS (31 KB total -> 5 blocks/CU).
//      h2 now written as TWO 32-channel tables: h2p[pass][node][32] ----
__global__ void k_sl1h2(const int* __restrict__ pk, const unsigned* __restrict__ bucketCursor,
                        unsigned cap,
                        const float* __restrict__ x, const float* __restrict__ SD,
                        const float* __restrict__ W1, const float* __restrict__ b1,
                        const float* __restrict__ W2, const float* __restrict__ attS,
                        const float* __restrict__ attD, int N,
                        unsigned* __restrict__ offsets, int* __restrict__ sortedSrc,
                        __half* __restrict__ h2p, float* __restrict__ aS, float* __restrict__ aD) {
    __shared__ int sorted[STAGE];
    __shared__ int cnt[BNODES];
    __shared__ int offl[BNODES];
    __shared__ float lds1[BNODES][36];    // stride 36: rows 16B-aligned for b128 reads
    int b = blockIdx.x, t = threadIdx.x;
    unsigned rbeg = (unsigned)b * cap;
    int m = (int)(bucketCursor[(size_t)b * 16] - rbeg);
    bool inLds = (m <= STAGE);
    int base = b << BSH;
    if (t < BNODES) cnt[t] = 0;
    __syncthreads();
    // pass 1: histogram from global pk (coalesced read, L2-warm)
    for (int i = t; i < m; i += TPB) atomicAdd(&cnt[pk[rbeg + i] & (BNODES - 1)], 1);
    __syncthreads();
    int v = (t < BNODES) ? cnt[t] : 0;
    if (t < BNODES) offl[t] = v;
    __syncthreads();
    for (int off = 1; off < BNODES; off <<= 1) {
        int u = (t >= off && t < BNODES) ? offl[t - off] : 0;
        __syncthreads();
        if (t < BNODES) offl[t] += u;
        __syncthreads();
    }
    if (t < BNODES) {
        int ex = offl[t] - v;
        int d = base + t;
        if (d < N) offsets[d] = ((rbeg + (unsigned)ex) << 10) | (unsigned)v;
        cnt[t] = 0;
        offl[t] = ex;
    }
    __syncthreads();
    // pass 2: reorder (second global read of pk, scattered LDS write)
    if (inLds) {
        for (int i = t; i < m; i += TPB) {
            int p = pk[rbeg + i];
            int dl = p & (BNODES - 1);
            int r = atomicAdd(&cnt[dl], 1);
            sorted[offl[dl] + r] = p >> BSH;
        }
        __syncthreads();
        for (int i = t; i < m; i += TPB) sortedSrc[rbeg + i] = sorted[i];
    } else {
        for (int i = t; i < m; i += TPB) {
            int p = pk[rbeg + i];
            int dl = p & (BNODES - 1);
            int r = atomicAdd(&cnt[dl], 1);
            sortedSrc[rbeg + (unsigned)(offl[dl] + r)] = p >> BSH;
        }
        __syncthreads();
    }
    __syncthreads();
    // layer-1 softmax: 2 threads/node; edge indices from LDS sorted[]
    int n = t >> 1, half = t & 1;
    int d2 = base + n;
    bool active = (d2 < N);
    float s0 = 0.f, s1 = 0.f, s2 = 0.f, s3 = 0.f;
    float g0 = 0.f, g1 = 0.f, g2 = 0.f, g3 = 0.f;
    if (active) {
        int deg = cnt[n];
        int lbeg = offl[n];
        float xd = x[d2];
        float S0 = SD[0], S1 = SD[1], S2 = SD[2], S3 = SD[3];
        float D0 = xd*SD[4], D1 = xd*SD[5], D2 = xd*SD[6], D3 = xd*SD[7];
        int dh = (deg + 1) >> 1;
        int i = lbeg + (half ? dh : 0);
        int rem = half ? (deg - dh) : dh;
        for (; rem >= 2; rem -= 2, i += 2) {
            int a0 = inLds ? sorted[i]   : sortedSrc[rbeg + i];
            int a1 = inLds ? sorted[i+1] : sortedSrc[rbeg + i + 1];
            float x0 = x[a0], x1 = x[a1];
            float p;
            p = __expf(lrelu(x0*S0 + D0)); s0 += p; g0 += p * x0;
            p = __expf(lrelu(x0*S1 + D1)); s1 += p; g1 += p * x0;
            p = __expf(lrelu(x0*S2 + D2)); s2 += p; g2 += p * x0;
            p = __expf(lrelu(x0*S3 + D3)); s3 += p; g3 += p * x0;
            p = __expf(lrelu(x1*S0 + D0)); s0 += p; g0 += p * x1;
            p = __expf(lrelu(x1*S1 + D1)); s1 += p; g1 += p * x1;
            p = __expf(lrelu(x1*S2 + D2)); s2 += p; g2 += p * x1;
            p = __expf(lrelu(x1*S3 + D3)); s3 += p; g3 += p * x1;
        }
        if (rem > 0) {
            int a0 = inLds ? sorted[i] : sortedSrc[rbeg + i];
            float xs = x[a0];
            float p;
            p = __expf(lrelu(xs*S0 + D0)); s0 += p; g0 += p * xs;
            p = __expf(lrelu(xs*S1 + D1)); s1 += p; g1 += p * xs;
            p = __expf(lrelu(xs*S2 + D2)); s2 += p; g2 += p * xs;
            p = __expf(lrelu(xs*S3 + D3)); s3 += p; g3 += p * xs;
        }
    }
    s0 += __shfl_xor(s0, 1); s1 += __shfl_xor(s1, 1);
    s2 += __shfl_xor(s2, 1); s3 += __shfl_xor(s3, 1);
    g0 += __shfl_xor(g0, 1); g1 += __shfl_xor(g1, 1);
    g2 += __shfl_xor(g2, 1); g3 += __shfl_xor(g3, 1);
    if (active) {
        float gg[4];
        gg[0] = g0 / (s0 + SEPS); gg[1] = g1 / (s1 + SEPS);
        gg[2] = g2 / (s2 + SEPS); gg[3] = g3 / (s3 + SEPS);
        int h0 = half * 2;                 // each half-thread writes 2 heads
        #pragma unroll
        for (int hh = 0; hh < 2; ++hh)
            #pragma unroll
            for (int cc = 0; cc < 8; ++cc)
                lds1[n][(h0+hh)*8+cc] = elu1(gg[h0+hh] * W1[(h0+hh)*8+cc] + b1[(h0+hh)*8+cc]);
    }
    __syncthreads();
    // h2 = lds1 @ W2 (+ att coeffs); write split tables h2p[lane>>5][node][lane&31]
    int lane = t & 63;                    // channel j
    int sub = t >> 6;                     // wave id 0..3
    float w2r[32];
    #pragma unroll
    for (int k = 0; k < 32; ++k) w2r[k] = W2[k*64 + lane];
    float attSl = attS[lane], attDl = attD[lane];
    size_t N32 = (size_t)N * 32;
    size_t tabOff = (size_t)(lane >> 5) * N32;
    int ch = lane & 31;
    int nCnt = min(BNODES, N - base);
    for (int nn = sub; nn < nCnt; nn += 4) {
        const float4* row4 = (const float4*)lds1[nn];
        float acc = 0.f;
        #pragma unroll
        for (int k4 = 0; k4 < 8; ++k4) {
            float4 rv = row4[k4];
            acc += rv.x*w2r[4*k4] + rv.y*w2r[4*k4+1] + rv.z*w2r[4*k4+2] + rv.w*w2r[4*k4+3];
        }
        int node = base + nn;
        h2p[tabOff + (size_t)node*32 + ch] = __float2half(acc);
        float ps = acc * attSl;
        float pd = acc * attDl;
        #pragma unroll
        for (int mm = 1; mm < 8; mm <<= 1) {
            ps += __shfl_xor(ps, mm);
            pd += __shfl_xor(pd, mm);
        }
        int hh = lane >> 3, cc = lane & 7;
        if (cc == 0) aS[(size_t)node*8 + hh] = ps;
        if (cc == 1) aD[(size_t)node*8 + hh] = pd;
    }
}

// ---- layer 2, one 4-head pass: wave = 4 edge-slots x 16 channel-pairs;
//      gathers 64B rows from a 6.4MB table (L2-friendlier than 12.8MB) ----
__global__ void k_aggp(const unsigned* __restrict__ offsets, const int* __restrict__ ss,
                       const float* __restrict__ aS, const float* __restrict__ aD,
                       const __half* __restrict__ h2p, const float* __restrict__ b2,
                       const float* __restrict__ fcw, const float* __restrict__ fcb,
                       float* __restrict__ out, int N, int pass) {
    __shared__ float pl[4][MAXDEG * 4];
    __shared__ int   sl[4][MAXDEG];
    int lane = threadIdx.x & 63;
    int w = threadIdx.x >> 6;
    int d = blockIdx.x * 4 + w;
    if (d >= N) return;
    unsigned u = offsets[d];
    unsigned beg = u >> 10;
    int deg = (int)(u & 1023u);
    int eS = lane >> 4;        // edge slot 0..3
    int pr = lane & 15;        // channel pair 0..15 -> channels 2pr, 2pr+1
    int hL = pr >> 2;          // local head 0..3
    int ho = pass * 4;         // global head offset
    const __half* tab = h2p + (size_t)pass * ((size_t)N * 32);
    float sum = 0.f, ax = 0.f, ay = 0.f;
    if (deg <= MAXDEG) {
        for (int j = lane; j < deg; j += 64) sl[w][j] = ss[beg + j];
        float adp = aD[(size_t)d*8 + ho + (lane & 3)];
        int tot = deg * 4;
        for (int base = 0; base < tot; base += 64) {
            int idx = base + lane;
            if (idx < tot) {
                int s = sl[w][idx >> 2];
                pl[w][idx] = __expf(lrelu(aS[(size_t)s*8 + ho + (lane & 3)] + adp));
            }
        }
        int e = 0;
        for (; e + 8 <= deg; e += 8) {
            int ea = e + eS, eb = e + 4 + eS;
            int sa = sl[w][ea], sb = sl[w][eb];
            float pa = pl[w][ea*4 + hL], pb = pl[w][eb*4 + hL];
            float2 ga = __half22float2(*(const __half2*)(tab + (size_t)sa*32 + 2*pr));
            float2 gb = __half22float2(*(const __half2*)(tab + (size_t)sb*32 + 2*pr));
            ax += pa*ga.x + pb*gb.x;
            ay += pa*ga.y + pb*gb.y;
            sum += pa + pb;
        }
        for (; e < deg; e += 4) {          // tail: chunks of 4 with predication
            int ea = e + eS;
            bool ok = ea < deg;
            int sa = sl[w][ok ? ea : 0];
            float pa = ok ? pl[w][ea*4 + hL] : 0.f;
            float2 ga = __half22float2(*(const __half2*)(tab + (size_t)sa*32 + 2*pr));
            ax += pa*ga.x; ay += pa*ga.y; sum += pa;
        }
    } else {
        // fallback (statistically never): edge slots stride edges
        float adh = aD[(size_t)d*8 + ho + hL];
        for (int e = eS; e < deg; e += 4) {
            int s = ss[beg + e];
            float p = __expf(lrelu(aS[(size_t)s*8 + ho + hL] + adh));
            float2 g = __half22float2(*(const __half2*)(tab + (size_t)s*32 + 2*pr));
            ax += p*g.x; ay += p*g.y; sum += p;
        }
    }
    // reduce over edge slots (xor 16, 32); sum becomes per-head total
    ax  += __shfl_xor(ax, 16);  ax  += __shfl_xor(ax, 32);
    ay  += __shfl_xor(ay, 16);  ay  += __shfl_xor(ay, 32);
    sum += __shfl_xor(sum, 16); sum += __shfl_xor(sum, 32);
    float inv = 1.f / (sum + SEPS);
    int co = pass * 32 + 2 * pr;
    float tt = elu1f(ax*inv + b2[co]) * fcw[co]
             + elu1f(ay*inv + b2[co+1]) * fcw[co+1];
    #pragma unroll
    for (int m = 8; m; m >>= 1) tt += __shfl_xor(tt, m);   // reduce 16 pairs
    if (lane == 0) {
        if (pass == 0) out[d] = tt + fcb[0];
        else           out[d] += tt;
    }
}

extern "C" void kernel_launch(void* const* d_in, const int* in_sizes, int n_in,
                              void* d_out, int out_size, void* d_ws, size_t ws_size,
                              hipStream_t stream) {
    const float* x    = (const float*)d_in[0];
    const int*   ei   = (const int*)  d_in[1];
    const float* W1   = (const float*)d_in[2];
    const float* as1  = (const float*)d_in[3];
    const float* ad1  = (const float*)d_in[4];
    const float* b1   = (const float*)d_in[5];
    const float* W2   = (const float*)d_in[6];
    const float* attS2= (const float*)d_in[7];
    const float* attD2= (const float*)d_in[8];
    const float* b2   = (const float*)d_in[9];
    const float* fcw  = (const float*)d_in[10];
    const float* fcb  = (const float*)d_in[11];
    float* out = (float*)d_out;

    int N = in_sizes[0];          // x is [N,1]
    int E = in_sizes[1] / 2;      // edge_index is [2,E]
    int ET = E + N;               // with self-loops
    int NB = (N + BNODES - 1) / BNODES;   // 128-node coarse buckets (<= NBMAX)
    unsigned cap = (unsigned)((ET + NB - 1) / NB + 512);
    cap = (cap + 3u) & ~3u;
    size_t padded = (size_t)NB * cap;

    const int* srcI = ei;
    const int* dstI = ei + E;

    float* ws = (float*)d_ws;
    size_t off = 0;
    float*    SD           = ws + off; off += 16;
    unsigned* bucketCursor = (unsigned*)(ws + off); off += (size_t)NBMAX * 16;
    unsigned* offsets      = (unsigned*)(ws + off); off += (size_t)N + 16;
    int*      pk           = (int*)(ws + off); off += padded;
    int*      sortedSrc    = (int*)(ws + off); off += padded;
    float*    aS2          = ws + off; off += (size_t)N * 8;
    float*    aD2          = ws + off; off += (size_t)N * 8;
    __half*   h2p          = (__half*)(ws + off); off += (size_t)N * 32;  // 2 tables x N*32 halves

    k_prep<<<1, 1024, 0, stream>>>(W1, as1, ad1, SD, bucketCursor, NB, cap);

    int chunk = (ET + NCHUNK - 1) / NCHUNK;
    k_bscatter<<<NCHUNK, SCTPB, 0, stream>>>(srcI, dstI, E, N, NB, chunk, bucketCursor, pk);
    k_sl1h2   <<<NB, TPB, 0, stream>>>(pk, bucketCursor, cap, x, SD, W1, b1, W2, attS2, attD2,
                                       N, offsets, sortedSrc, h2p, aS2, aD2);
    k_aggp    <<<(N + 3) / 4, TPB, 0, stream>>>(offsets, sortedSrc, aS2, aD2, h2p,
                                                b2, fcw, fcb, out, N, 0);
    k_aggp    <<<(N + 3) / 4, TPB, 0, stream>>>(offsets, sortedSrc, aS2, aD2, h2p,
                                                b2, fcw, fcb, out, N, 1);
}

// Round 22
// 214.416 us; speedup vs baseline: 1.2341x; 1.2341x over previous
//
#include <hip/hip_runtime.h>
#include <hip/hip_fp16.h>
#include <cmath>

#define TPB 256
#define NSLOPE 0.2f
#define SEPS 1e-16f

#define BSH 7                 // nodes per bucket = 128
#define BNODES 128
#define NBMAX 1024            // supports N up to 131072 at BSH=7
#define NCHUNK 512            // blocks for bucket scatter
#define SCTPB 1024            // bscatter threads
#define SCSTAGE 3360          // bscatter per-chunk LDS staging (chunk=3321 at N=100k)
#define STAGE 2816            // per-bucket LDS sorted-edge staging (cap=2688 at N=100k)
#define MAXDEG 96             // per-wave LDS score staging cap (P[deg>96] ~ 0 for Poisson(17))

__device__ __forceinline__ float lrelu(float v) { return v > 0.f ? v : NSLOPE * v; }
__device__ __forceinline__ float elu1(float v)  { return v > 0.f ? v : expm1f(v); }
__device__ __forceinline__ float elu1f(float v) { return v > 0.f ? v : __expf(v) - 1.f; }

// ---- prep: SD[0..3]=S1[h], SD[4..7]=D1[h]; init padded-bucket cursors (1/64B line) ----
__global__ void k_prep(const float* __restrict__ W1, const float* __restrict__ as1,
                       const float* __restrict__ ad1, float* __restrict__ SD,
                       unsigned* __restrict__ bucketCursor, int NB, unsigned cap) {
    int t = threadIdx.x;
    for (int i = t; i < NB; i += blockDim.x) bucketCursor[(size_t)i * 16] = (unsigned)i * cap;
    if (t < 8) {
        int h = t & 3;
        const float* att = (t >= 4) ? ad1 : as1;
        float acc = 0.f;
        #pragma unroll
        for (int c = 0; c < 8; ++c) acc += W1[h*8+c] * att[h*8+c];
        SD[t] = acc;
    }
}

// ---- bucket scatter: hist -> scan -> claim -> LDS bucket-sort of the chunk ->
//      LINEAR bucket-coalesced global writes ----
__global__ void k_bscatter(const int* __restrict__ srcI, const int* __restrict__ dstI,
                           int E, int N, int NB, int chunk,
                           unsigned* __restrict__ bucketCursor, int* __restrict__ pk) {
    __shared__ int cnt[NBMAX];
    __shared__ unsigned base[NBMAX];      // scan scratch, then claimed bases
    __shared__ int offl[NBMAX];           // local exclusive prefix
    __shared__ int rval[SCSTAGE];
    __shared__ unsigned short rbkt[SCSTAGE];
    int t = threadIdx.x;
    int ET = E + N;
    int beg = blockIdx.x * chunk;
    int end = min(beg + chunk, ET);
    int m = end - beg;
    for (int i = t; i < NBMAX; i += blockDim.x) cnt[i] = 0;
    __syncthreads();
    for (int e = beg + t; e < end; e += blockDim.x) {
        int d = (e < E) ? dstI[e] : (e - E);
        atomicAdd(&cnt[d >> BSH], 1);
    }
    __syncthreads();
    int v = (t < NBMAX) ? cnt[t] : 0;
    if (t < NBMAX) base[t] = (unsigned)v;
    __syncthreads();
    for (int off = 1; off < NBMAX; off <<= 1) {
        unsigned u = (t >= off && t < NBMAX) ? base[t - off] : 0u;
        __syncthreads();
        if (t < NBMAX) base[t] += u;
        __syncthreads();
    }
    if (t < NBMAX) offl[t] = (int)base[t] - v;   // exclusive prefix within chunk
    __syncthreads();
    if (t < NB) {
        base[t] = v ? atomicAdd(&bucketCursor[(size_t)t * 16], (unsigned)v) : 0u;
        cnt[t] = 0;
    }
    __syncthreads();
    if (m <= SCSTAGE) {
        for (int e = beg + t; e < end; e += blockDim.x) {
            int s, d;
            if (e < E) { s = srcI[e]; d = dstI[e]; } else { s = d = e - E; }
            int b = d >> BSH;
            int r = atomicAdd(&cnt[b], 1);
            int slot = offl[b] + r;
            rval[slot] = (s << BSH) | (d & (BNODES - 1));
            rbkt[slot] = (unsigned short)b;
        }
        __syncthreads();
        for (int slot = t; slot < m; slot += blockDim.x) {
            int b = rbkt[slot];
            pk[base[b] + (unsigned)(slot - offl[b])] = rval[slot];
        }
    } else {
        for (int e = beg + t; e < end; e += blockDim.x) {
            int s, d;
            if (e < E) { s = srcI[e]; d = dstI[e]; } else { s = d = e - E; }
            int b = d >> BSH;
            int r = atomicAdd(&cnt[b], 1);
            pk[base[b] + (unsigned)r] = (s << BSH) | (d & (BNODES - 1));
        }
    }
}

// ---- merged sort + layer-1 + h2/att: pk read twice from global (L2-warm);
//      sorted list lives in LDS (31 KB total -> 5 blocks/CU) ----
__global__ void k_sl1h2(const int* __restrict__ pk, const unsigned* __restrict__ bucketCursor,
                        unsigned cap,
                        const float* __restrict__ x, const float* __restrict__ SD,
                        const float* __restrict__ W1, const float* __restrict__ b1,
                        const float* __restrict__ W2, const float* __restrict__ attS,
                        const float* __restrict__ attD, int N,
                        unsigned* __restrict__ offsets, int* __restrict__ sortedSrc,
                        __half* __restrict__ h2h, float* __restrict__ aS, float* __restrict__ aD) {
    __shared__ int sorted[STAGE];
    __shared__ int cnt[BNODES];
    __shared__ int offl[BNODES];
    __shared__ float lds1[BNODES][36];    // stride 36: rows 16B-aligned for b128 reads
    int b = blockIdx.x, t = threadIdx.x;
    unsigned rbeg = (unsigned)b * cap;
    int m = (int)(bucketCursor[(size_t)b * 16] - rbeg);
    bool inLds = (m <= STAGE);
    int base = b << BSH;
    if (t < BNODES) cnt[t] = 0;
    __syncthreads();
    // pass 1: histogram from global pk (coalesced read, L2-warm)
    for (int i = t; i < m; i += TPB) atomicAdd(&cnt[pk[rbeg + i] & (BNODES - 1)], 1);
    __syncthreads();
    int v = (t < BNODES) ? cnt[t] : 0;
    if (t < BNODES) offl[t] = v;
    __syncthreads();
    for (int off = 1; off < BNODES; off <<= 1) {
        int u = (t >= off && t < BNODES) ? offl[t - off] : 0;
        __syncthreads();
        if (t < BNODES) offl[t] += u;
        __syncthreads();
    }
    if (t < BNODES) {
        int ex = offl[t] - v;
        int d = base + t;
        if (d < N) offsets[d] = ((rbeg + (unsigned)ex) << 10) | (unsigned)v;
        cnt[t] = 0;
        offl[t] = ex;
    }
    __syncthreads();
    // pass 2: reorder (second global read of pk, scattered LDS write)
    if (inLds) {
        for (int i = t; i < m; i += TPB) {
            int p = pk[rbeg + i];
            int dl = p & (BNODES - 1);
            int r = atomicAdd(&cnt[dl], 1);
            sorted[offl[dl] + r] = p >> BSH;
        }
        __syncthreads();
        for (int i = t; i < m; i += TPB) sortedSrc[rbeg + i] = sorted[i];
    } else {
        for (int i = t; i < m; i += TPB) {
            int p = pk[rbeg + i];
            int dl = p & (BNODES - 1);
            int r = atomicAdd(&cnt[dl], 1);
            sortedSrc[rbeg + (unsigned)(offl[dl] + r)] = p >> BSH;
        }
        __syncthreads();
    }
    __syncthreads();
    // layer-1 softmax: 2 threads/node; edge indices from LDS sorted[]
    int n = t >> 1, half = t & 1;
    int d2 = base + n;
    bool active = (d2 < N);
    float s0 = 0.f, s1 = 0.f, s2 = 0.f, s3 = 0.f;
    float g0 = 0.f, g1 = 0.f, g2 = 0.f, g3 = 0.f;
    if (active) {
        int deg = cnt[n];
        int lbeg = offl[n];
        float xd = x[d2];
        float S0 = SD[0], S1 = SD[1], S2 = SD[2], S3 = SD[3];
        float D0 = xd*SD[4], D1 = xd*SD[5], D2 = xd*SD[6], D3 = xd*SD[7];
        int dh = (deg + 1) >> 1;
        int i = lbeg + (half ? dh : 0);
        int rem = half ? (deg - dh) : dh;
        for (; rem >= 2; rem -= 2, i += 2) {
            int a0 = inLds ? sorted[i]   : sortedSrc[rbeg + i];
            int a1 = inLds ? sorted[i+1] : sortedSrc[rbeg + i + 1];
            float x0 = x[a0], x1 = x[a1];
            float p;
            p = __expf(lrelu(x0*S0 + D0)); s0 += p; g0 += p * x0;
            p = __expf(lrelu(x0*S1 + D1)); s1 += p; g1 += p * x0;
            p = __expf(lrelu(x0*S2 + D2)); s2 += p; g2 += p * x0;
            p = __expf(lrelu(x0*S3 + D3)); s3 += p; g3 += p * x0;
            p = __expf(lrelu(x1*S0 + D0)); s0 += p; g0 += p * x1;
            p = __expf(lrelu(x1*S1 + D1)); s1 += p; g1 += p * x1;
            p = __expf(lrelu(x1*S2 + D2)); s2 += p; g2 += p * x1;
            p = __expf(lrelu(x1*S3 + D3)); s3 += p; g3 += p * x1;
        }
        if (rem > 0) {
            int a0 = inLds ? sorted[i] : sortedSrc[rbeg + i];
            float xs = x[a0];
            float p;
            p = __expf(lrelu(xs*S0 + D0)); s0 += p; g0 += p * xs;
            p = __expf(lrelu(xs*S1 + D1)); s1 += p; g1 += p * xs;
            p = __expf(lrelu(xs*S2 + D2)); s2 += p; g2 += p * xs;
            p = __expf(lrelu(xs*S3 + D3)); s3 += p; g3 += p * xs;
        }
    }
    s0 += __shfl_xor(s0, 1); s1 += __shfl_xor(s1, 1);
    s2 += __shfl_xor(s2, 1); s3 += __shfl_xor(s3, 1);
    g0 += __shfl_xor(g0, 1); g1 += __shfl_xor(g1, 1);
    g2 += __shfl_xor(g2, 1); g3 += __shfl_xor(g3, 1);
    if (active) {
        float gg[4];
        gg[0] = g0 / (s0 + SEPS); gg[1] = g1 / (s1 + SEPS);
        gg[2] = g2 / (s2 + SEPS); gg[3] = g3 / (s3 + SEPS);
        int h0 = half * 2;                 // each half-thread writes 2 heads
        #pragma unroll
        for (int hh = 0; hh < 2; ++hh)
            #pragma unroll
            for (int cc = 0; cc < 8; ++cc)
                lds1[n][(h0+hh)*8+cc] = elu1(gg[h0+hh] * W1[(h0+hh)*8+cc] + b1[(h0+hh)*8+cc]);
    }
    __syncthreads();
    // h2 = lds1 @ W2 (+ att coeffs); W2 column in 32 VGPRs, row via b128 reads.
    int lane = t & 63;                    // channel j
    int sub = t >> 6;                     // wave id 0..3
    float w2r[32];
    #pragma unroll
    for (int k = 0; k < 32; ++k) w2r[k] = W2[k*64 + lane];
    float attSl = attS[lane], attDl = attD[lane];
    int nCnt = min(BNODES, N - base);
    for (int nn = sub; nn < nCnt; nn += 4) {
        const float4* row4 = (const float4*)lds1[nn];
        float acc = 0.f;
        #pragma unroll
        for (int k4 = 0; k4 < 8; ++k4) {
            float4 rv = row4[k4];
            acc += rv.x*w2r[4*k4] + rv.y*w2r[4*k4+1] + rv.z*w2r[4*k4+2] + rv.w*w2r[4*k4+3];
        }
        int node = base + nn;
        h2h[(size_t)node*64 + lane] = __float2half(acc);
        float ps = acc * attSl;
        float pd = acc * attDl;
        #pragma unroll
        for (int mm = 1; mm < 8; mm <<= 1) {
            ps += __shfl_xor(ps, mm);
            pd += __shfl_xor(pd, mm);
        }
        int hh = lane >> 3, cc = lane & 7;
        if (cc == 0) aS[(size_t)node*8 + hh] = ps;
        if (cc == 1) aD[(size_t)node*8 + hh] = pd;
    }
}

// ---- layer 2: wave-per-node; half2 lane-split — lanes 0-31 = channel pairs of even
//      edges, lanes 32-63 = odd edges; halves merged with one shfl_xor(.,32) ----
__global__ void k_agg(const unsigned* __restrict__ offsets, const int* __restrict__ ss,
                      const float* __restrict__ aS, const float* __restrict__ aD,
                      const __half* __restrict__ h2h, const float* __restrict__ b2,
                      const float* __restrict__ fcw, const float* __restrict__ fcb,
                      float* __restrict__ out, int N) {
    __shared__ float pl[4][MAXDEG * 8];
    __shared__ int   sl[4][MAXDEG];
    int lane = threadIdx.x & 63;
    int w = threadIdx.x >> 6;
    int d = blockIdx.x * 4 + w;
    if (d >= N) return;
    unsigned u = offsets[d];
    unsigned beg = u >> 10;
    int deg = (int)(u & 1023u);
    int lH   = lane & 31;      // channel pair: channels 2lH, 2lH+1 (same head always)
    int half = lane >> 5;      // 0 -> even edges, 1 -> odd edges
    int hh   = lH >> 2;        // head of my channel pair
    float sum = 0.f, ax = 0.f, ay = 0.f;
    if (deg <= MAXDEG) {
        for (int j = lane; j < deg; j += 64) sl[w][j] = ss[beg + j];
        float adp = aD[(size_t)d*8 + (lane & 7)];
        int tot = deg * 8;
        for (int base = 0; base < tot; base += 64) {
            int idx = base + lane;
            if (idx < tot) {
                int s = sl[w][idx >> 3];
                pl[w][idx] = __expf(lrelu(aS[(size_t)s*8 + (lane & 7)] + adp));
            }
        }
        int e = 0;
        for (; e + 8 <= deg; e += 8) {
            int e0 = e + half, e1 = e + 2 + half, e2 = e + 4 + half, e3 = e + 6 + half;
            int s0 = sl[w][e0], s1 = sl[w][e1], s2 = sl[w][e2], s3 = sl[w][e3];
            float p0 = pl[w][e0*8 + hh], p1 = pl[w][e1*8 + hh];
            float p2 = pl[w][e2*8 + hh], p3 = pl[w][e3*8 + hh];
            float2 g0 = __half22float2(*(const __half2*)(h2h + (size_t)s0*64 + 2*lH));
            float2 g1 = __half22float2(*(const __half2*)(h2h + (size_t)s1*64 + 2*lH));
            float2 g2 = __half22float2(*(const __half2*)(h2h + (size_t)s2*64 + 2*lH));
            float2 g3 = __half22float2(*(const __half2*)(h2h + (size_t)s3*64 + 2*lH));
            ax += p0*g0.x + p1*g1.x + p2*g2.x + p3*g3.x;
            ay += p0*g0.y + p1*g1.y + p2*g2.y + p3*g3.y;
            sum += (p0 + p1) + (p2 + p3);
        }
        for (; e + 2 <= deg; e += 2) {
            int e0 = e + half;
            int s0 = sl[w][e0];
            float p0 = pl[w][e0*8 + hh];
            float2 g0 = __half22float2(*(const __half2*)(h2h + (size_t)s0*64 + 2*lH));
            ax += p0*g0.x; ay += p0*g0.y; sum += p0;
        }
        if (e < deg) {                      // odd tail: only half==0 contributes
            int s0 = sl[w][e];
            float p0 = (half == 0) ? pl[w][e*8 + hh] : 0.f;
            float2 g0 = __half22float2(*(const __half2*)(h2h + (size_t)s0*64 + 2*lH));
            ax += p0*g0.x; ay += p0*g0.y; sum += p0;
        }
    } else {
        // fallback (statistically never): halves take strided edges
        float adh = aD[(size_t)d*8 + hh];
        for (int e = half; e < deg; e += 2) {
            int s = ss[beg + e];
            float p = __expf(lrelu(aS[(size_t)s*8 + hh] + adh));
            float2 g = __half22float2(*(const __half2*)(h2h + (size_t)s*64 + 2*lH));
            ax += p*g.x; ay += p*g.y; sum += p;
        }
    }
    ax  += __shfl_xor(ax, 32);
    ay  += __shfl_xor(ay, 32);
    sum += __shfl_xor(sum, 32);
    float inv = 1.f / (sum + SEPS);
    float tt = elu1f(ax*inv + b2[2*lH]) * fcw[2*lH]
             + elu1f(ay*inv + b2[2*lH+1]) * fcw[2*lH+1];
    #pragma unroll
    for (int m = 16; m; m >>= 1) tt += __shfl_xor(tt, m);
    if (lane == 0) out[d] = tt + fcb[0];
}

extern "C" void kernel_launch(void* const* d_in, const int* in_sizes, int n_in,
                              void* d_out, int out_size, void* d_ws, size_t ws_size,
                              hipStream_t stream) {
    const float* x    = (const float*)d_in[0];
    const int*   ei   = (const int*)  d_in[1];
    const float* W1   = (const float*)d_in[2];
    const float* as1  = (const float*)d_in[3];
    const float* ad1  = (const float*)d_in[4];
    const float* b1   = (const float*)d_in[5];
    const float* W2   = (const float*)d_in[6];
    const float* attS2= (const float*)d_in[7];
    const float* attD2= (const float*)d_in[8];
    const float* b2   = (const float*)d_in[9];
    const float* fcw  = (const float*)d_in[10];
    const float* fcb  = (const float*)d_in[11];
    float* out = (float*)d_out;

    int N = in_sizes[0];          // x is [N,1]
    int E = in_sizes[1] / 2;      // edge_index is [2,E]
    int ET = E + N;               // with self-loops
    int NB = (N + BNODES - 1) / BNODES;   // 128-node coarse buckets (<= NBMAX)
    // padded bucket capacity: mean + 512 (~11 sigma for Binomial(ET,1/NB)), 4-aligned
    unsigned cap = (unsigned)((ET + NB - 1) / NB + 512);
    cap = (cap + 3u) & ~3u;
    size_t padded = (size_t)NB * cap;

    const int* srcI = ei;
    const int* dstI = ei + E;

    float* ws = (float*)d_ws;
    size_t off = 0;
    float*    SD           = ws + off; off += 16;
    unsigned* bucketCursor = (unsigned*)(ws + off); off += (size_t)NBMAX * 16;
    unsigned* offsets      = (unsigned*)(ws + off); off += (size_t)N + 16;
    int*      pk           = (int*)(ws + off); off += padded;
    int*      sortedSrc    = (int*)(ws + off); off += padded;
    float*    aS2          = ws + off; off += (size_t)N * 8;
    float*    aD2          = ws + off; off += (size_t)N * 8;
    __half*   h2h          = (__half*)(ws + off); off += (size_t)N * 32;  // N*64 halves

    k_prep<<<1, 1024, 0, stream>>>(W1, as1, ad1, SD, bucketCursor, NB, cap);

    int chunk = (ET + NCHUNK - 1) / NCHUNK;
    k_bscatter<<<NCHUNK, SCTPB, 0, stream>>>(srcI, dstI, E, N, NB, chunk, bucketCursor, pk);
    k_sl1h2   <<<NB, TPB, 0, stream>>>(pk, bucketCursor, cap, x, SD, W1, b1, W2, attS2, attD2,
                                       N, offsets, sortedSrc, h2h, aS2, aD2);
    k_agg     <<<(N + 3) / 4, TPB, 0, stream>>>(offsets, sortedSrc, aS2, aD2, h2h,
                                                b2, fcw, fcb, out, N);
}